// Round 1
// 383.811 us; speedup vs baseline: 1.1229x; 1.1229x over previous
//
#include <hip/hip_runtime.h>
#include <hip/hip_bf16.h>
#include <math.h>

// B=64, NS=16, NF=4096, D=128, H=256. All tensors fp32; bf16 packing is used
// internally (k/v/q) for the attention dot-products only.
#define B_  64
#define NS_ 16
#define NF_ 4096
#define D_  128
#define H_  256

// ws layout (bytes):
//   [0      , 262144): q as bf16 pairs [B][NS][D]
//   [262144 , 786432): attended accumulator fp32 [B][NS][D]
//   [786432 , 790528): denom fp32 [B][NS]

__device__ __forceinline__ float bflo(unsigned int u) { return __uint_as_float(u << 16); }
__device__ __forceinline__ float bfhi(unsigned int u) { return __uint_as_float(u & 0xffff0000u); }

// pack two fp32 -> bf16 pair with round-to-nearest-even
__device__ __forceinline__ unsigned int pk_bf16(float a, float b) {
    unsigned int ua = __float_as_uint(a), ub = __float_as_uint(b);
    ua = (ua + 0x7FFFu + ((ua >> 16) & 1u)) >> 16;
    ub = (ub + 0x7FFFu + ((ub >> 16) & 1u)) >> 16;
    return ua | (ub << 16);
}

__device__ __forceinline__ float dot2_bf16(unsigned int a, unsigned int b, float c) {
    float d;
    asm("v_dot2_f32_bf16 %0, %1, %2, %3" : "=v"(d) : "v"(a), "v"(b), "v"(c));
    return d;
}

__device__ __forceinline__ float dot4(float4 a, float4 b) {
    return a.x * b.x + a.y * b.y + a.z * b.z + a.w * b.w;
}

// ---------------- Kernel 1: per-batch LN(slots) @ Wq^T -> q (bf16 pairs) ----
// grid 64 (=b), 128 threads. Wq row per thread loaded ONCE, reused for 16 n.
__global__ __launch_bounds__(128) void k_q(
    const float* __restrict__ slots, const float* __restrict__ Wq,
    const float* __restrict__ lng, const float* __restrict__ lnb,
    unsigned int* __restrict__ q_out, float* __restrict__ acc, float* __restrict__ den) {
    const int b = blockIdx.x;
    const int t = threadIdx.x;  // 0..127
    __shared__ float sl_s[16][128];
    __shared__ float norm_s[16][128];
    __shared__ float st_s[16][8][2];
    __shared__ float mu_s[16], rs_s[16];
    __shared__ float q_s[16][128];

    // load slots[b]: 512 float4s
    const float4* sp = (const float4*)(slots + (size_t)b * 2048);
#pragma unroll
    for (int i = 0; i < 4; ++i) {
        int f = i * 128 + t;
        *(float4*)&sl_s[f >> 5][(f & 31) * 4] = sp[f];
    }
    __syncthreads();

    // stats: thread (n = t>>3, j = t&7) over 16 d's
    {
        int n = t >> 3, j = t & 7;
        float s1 = 0.f, s2 = 0.f;
#pragma unroll
        for (int d2 = 0; d2 < 16; ++d2) {
            float x = sl_s[n][j * 16 + d2];
            s1 += x; s2 += x * x;
        }
        st_s[n][j][0] = s1; st_s[n][j][1] = s2;
    }
    __syncthreads();
    if (t < 16) {
        float s1 = 0.f, s2 = 0.f;
#pragma unroll
        for (int j = 0; j < 8; ++j) { s1 += st_s[t][j][0]; s2 += st_s[t][j][1]; }
        float mu = s1 * (1.0f / 128.0f);
        float var = s2 * (1.0f / 128.0f) - mu * mu;
        mu_s[t] = mu;
        rs_s[t] = rsqrtf(var + 1e-5f);
    }
    __syncthreads();

    float gl = lng[t], bl = lnb[t];
#pragma unroll
    for (int n = 0; n < 16; ++n)
        norm_s[n][t] = (sl_s[n][t] - mu_s[n]) * rs_s[n] * gl + bl;
    __syncthreads();

    // q[n][e=t] = sum_d norm[n][d]*Wq[e][d]; Wq row loaded once
    const float4* wq = (const float4*)(Wq + (size_t)t * 128);
    float qn[16];
#pragma unroll
    for (int n = 0; n < 16; ++n) qn[n] = 0.f;
#pragma unroll 4
    for (int j = 0; j < 32; ++j) {
        float4 w4 = wq[j];
#pragma unroll
        for (int n = 0; n < 16; ++n) qn[n] += dot4(w4, *(const float4*)&norm_s[n][4 * j]);
    }
#pragma unroll
    for (int n = 0; n < 16; ++n) q_s[n][t] = qn[n];

    // zero acc for this batch + den
    float4 z4 = make_float4(0.f, 0.f, 0.f, 0.f);
    float4* ab = (float4*)(acc + (size_t)b * 2048);
#pragma unroll
    for (int i = 0; i < 4; ++i) ab[i * 128 + t] = z4;
    if (t < 16) den[b * 16 + t] = 0.f;
    __syncthreads();

    // pack q to bf16 pairs: 1024 uints
    unsigned int* qo = q_out + (size_t)b * 1024;
#pragma unroll
    for (int i = 0; i < 8; ++i) {
        int u = i * 128 + t;
        int n = u >> 6, e2 = u & 63;
        qo[n * 64 + e2] = pk_bf16(q_s[n][2 * e2], q_s[n][2 * e2 + 1]);
    }
}

// ---------------- Kernel 2: fused attention, wave-autonomous ---------------
// grid (16 chunks, 64 batches) x 256 threads. Wave w owns m-range
// [chunk*256 + w*64, +64) in 4 tiles of 16; NO barriers in the main loop.
// waves_per_eu(2,2): per-lane live set is ~190 VGPRs (qreg 64 + acc 32 +
// cur/prefetch k/v 64 + temps). Pinning max waves at 2/SIMD caps VGPRs at
// 256 and defeats the scheduler's occupancy heuristic that previously
// targeted 6 waves/SIMD (VGPR_Count=84) and spilled ~100 regs to scratch
// (~130 MB/dispatch of WRITE_SIZE). 8 waves/CU matches measured occupancy
// anyway; latency hiding comes from the software prefetch.
__global__ __launch_bounds__(256) __attribute__((amdgpu_waves_per_eu(2, 2)))
void k_attn(
    const float* __restrict__ kg_, const float* __restrict__ vg_,
    const unsigned int* __restrict__ q_u, float* __restrict__ acc_g, float* __restrict__ denom_g) {
    const int t = threadIdx.x;
    const int w = t >> 6, l = t & 63;
    const int b = blockIdx.y;
    const int n = l & 15;
    const int q4 = l >> 4;

    // per-wave LDS slice: k 16x68, v 16x68, p 16x20(float)  = 2496 dwords
    __shared__ unsigned int lds_u[9984];
    unsigned int* k_s = lds_u + w * 2496;
    unsigned int* v_s = k_s + 1088;
    float*        p_s = (float*)(k_s + 2176);

    // q row for this lane's n: 128 bf16 = 16 uint4
    uint4 qreg[16];
    {
        const uint4* qrow = (const uint4*)q_u + ((b * 16 + n) * 16);
#pragma unroll
        for (int jj = 0; jj < 16; ++jj) qreg[jj] = qrow[jj];
    }

    float accL[16], accH[16];
#pragma unroll
    for (int i = 0; i < 16; ++i) { accL[i] = 0.f; accH[i] = 0.f; }
    float denom_acc = 0.f;

    const size_t mbase = (size_t)b * NF_ + blockIdx.x * 256 + w * 64;
    const float4* kg4 = (const float4*)kg_ + mbase * 32;  // 32 float4 per row
    const float4* vg4 = (const float4*)vg_ + mbase * 32;

    // prologue: load+pack tile 0 (each lane: 8 float4 of k, 8 of v, coalesced)
    uint2 kc[8], vc[8], kn2[8], vn2[8];
#pragma unroll
    for (int i = 0; i < 8; ++i) {
        float4 kk = kg4[i * 64 + l];
        float4 vv = vg4[i * 64 + l];
        kc[i] = make_uint2(pk_bf16(kk.x, kk.y), pk_bf16(kk.z, kk.w));
        vc[i] = make_uint2(pk_bf16(vv.x, vv.y), pk_bf16(vv.z, vv.w));
    }

    for (int tile = 0; tile < 4; ++tile) {
        // stage current tile to LDS (row r = 2i + (l>>5), dword col 2*(l&31))
#pragma unroll
        for (int i = 0; i < 8; ++i) {
            int off = (2 * i + (l >> 5)) * 68 + 2 * (l & 31);
            *(uint2*)&k_s[off] = kc[i];
            *(uint2*)&v_s[off] = vc[i];
        }
        // prefetch next tile (loads in flight during compute)
        if (tile < 3) {
            const float4* kp = kg4 + (tile + 1) * 512;
            const float4* vp = vg4 + (tile + 1) * 512;
#pragma unroll
            for (int i = 0; i < 8; ++i) {
                float4 kk = kp[i * 64 + l];
                float4 vv = vp[i * 64 + l];
                kn2[i] = make_uint2(pk_bf16(kk.x, kk.y), pk_bf16(kk.z, kk.w));
                vn2[i] = make_uint2(pk_bf16(vv.x, vv.y), pk_bf16(vv.z, vv.w));
            }
        }

        // phase 1: logits + softmax over n, 4 m-rows per pass
#pragma unroll
        for (int pass = 0; pass < 4; ++pass) {
            const int mi1 = pass * 4 + q4;
            float lg = 0.f;
#pragma unroll
            for (int jj = 0; jj < 16; ++jj) {
                uint4 kk = *(const uint4*)&k_s[mi1 * 68 + 4 * jj];
                lg = dot2_bf16(kk.x, qreg[jj].x, lg);
                lg = dot2_bf16(kk.y, qreg[jj].y, lg);
                lg = dot2_bf16(kk.z, qreg[jj].z, lg);
                lg = dot2_bf16(kk.w, qreg[jj].w, lg);
            }
            lg *= 0.08838834764831845f;  // D^-0.5
            float mx = lg;
            mx = fmaxf(mx, __shfl_xor(mx, 1));
            mx = fmaxf(mx, __shfl_xor(mx, 2));
            mx = fmaxf(mx, __shfl_xor(mx, 4));
            mx = fmaxf(mx, __shfl_xor(mx, 8));
            float e = __expf(lg - mx);
            float se = e;
            se += __shfl_xor(se, 1);
            se += __shfl_xor(se, 2);
            se += __shfl_xor(se, 4);
            se += __shfl_xor(se, 8);
            float pv = e / se;
            denom_acc += pv;
            p_s[mi1 * 20 + n] = pv;
        }

        // phase 2: acc[n][2l,2l+1] += p[mi][n] * v[mi][2l,2l+1]
#pragma unroll 4
        for (int mi = 0; mi < 16; ++mi) {
            unsigned int vv2 = v_s[mi * 68 + l];
            float vlo = bflo(vv2), vhi = bfhi(vv2);
            float pv16[16];
            *(float4*)&pv16[0]  = *(const float4*)&p_s[mi * 20 + 0];
            *(float4*)&pv16[4]  = *(const float4*)&p_s[mi * 20 + 4];
            *(float4*)&pv16[8]  = *(const float4*)&p_s[mi * 20 + 8];
            *(float4*)&pv16[12] = *(const float4*)&p_s[mi * 20 + 12];
#pragma unroll
            for (int nn = 0; nn < 16; ++nn) {
                accL[nn] = fmaf(pv16[nn], vlo, accL[nn]);
                accH[nn] = fmaf(pv16[nn], vhi, accH[nn]);
            }
        }

#pragma unroll
        for (int i = 0; i < 8; ++i) { kc[i] = kn2[i]; vc[i] = vn2[i]; }
    }

    // ---- epilogue: cross-wave reduce (LDS reused), atomics ----
    __syncthreads();
    float* red_f = (float*)lds_u;           // [3][16][128]
    float* red_d = (float*)lds_u + 6144;    // [256]
    red_d[t] = denom_acc;
    if (w > 0) {
#pragma unroll
        for (int nn = 0; nn < 16; ++nn)
            *(float2*)&red_f[(w - 1) * 2048 + nn * 128 + 2 * l] = make_float2(accL[nn], accH[nn]);
    }
    __syncthreads();
    if (w == 0) {
        float* base = acc_g + (size_t)(b * 16) * 128;
#pragma unroll
        for (int nn = 0; nn < 16; ++nn) {
            float2 r0 = *(const float2*)&red_f[0 * 2048 + nn * 128 + 2 * l];
            float2 r1 = *(const float2*)&red_f[1 * 2048 + nn * 128 + 2 * l];
            float2 r2 = *(const float2*)&red_f[2 * 2048 + nn * 128 + 2 * l];
            atomicAdd(base + nn * 128 + 2 * l,     accL[nn] + r0.x + r1.x + r2.x);
            atomicAdd(base + nn * 128 + 2 * l + 1, accH[nn] + r0.y + r1.y + r2.y);
        }
    }
    if (t < 16) {
        float s = 0.f;
#pragma unroll
        for (int j = 0; j < 16; ++j) s += red_d[t + 16 * j];
        atomicAdd(denom_g + b * 16 + t, s);
    }
}

// ---------------- Kernel 3: GRU + LN + MLP + residual, 4 bn per block ------
__global__ __launch_bounds__(256) void k_final(
    const float* __restrict__ acc_g, const float* __restrict__ denom_g,
    const float* __restrict__ slots,
    const float* __restrict__ W_ih, const float* __restrict__ W_hh,
    const float* __restrict__ b_ih, const float* __restrict__ b_n,
    const float* __restrict__ ffg, const float* __restrict__ ffb,
    const float* __restrict__ W0, const float* __restrict__ b0,
    const float* __restrict__ W1, const float* __restrict__ b1,
    float* __restrict__ out) {
    const int bn0 = blockIdx.x * 4;
    const int t = threadIdx.x;  // 0..255
    __shared__ float att_s[4][128], slot_s[4][128];
    __shared__ float gates_s[4][4][128];  // [bn][rs,is,in,hn][d]
    __shared__ float gru_s[4][128], gn_s[4][128];
    __shared__ float h_s[4][256];

    // load att/slot
#pragma unroll
    for (int idx = t; idx < 512; idx += 256) {
        int bi = idx >> 7, d = idx & 127;
        int bn = bn0 + bi;
        float den = denom_g[bn] + 1e-8f;
        att_s[bi][d] = acc_g[(size_t)bn * 128 + d] / den;
        slot_s[bi][d] = slots[(size_t)bn * 128 + d];
    }
    __syncthreads();

    // gates: rows 0..383 (t<128 handles two rows)
    for (int g = t; g < 384; g += 256) {
        const float4* wi = (const float4*)(W_ih + (size_t)g * 128);
        const float4* wh = (const float4*)(W_hh + (size_t)g * 128);
        float si[4] = {0.f, 0.f, 0.f, 0.f}, sh[4] = {0.f, 0.f, 0.f, 0.f};
#pragma unroll 4
        for (int j = 0; j < 32; ++j) {
            float4 wi4 = wi[j], wh4 = wh[j];
#pragma unroll
            for (int bi = 0; bi < 4; ++bi) {
                si[bi] += dot4(wi4, *(const float4*)&att_s[bi][4 * j]);
                sh[bi] += dot4(wh4, *(const float4*)&slot_s[bi][4 * j]);
            }
        }
        float bih = b_ih[g];
        int d = g & 127;
#pragma unroll
        for (int bi = 0; bi < 4; ++bi) {
            if (g < 128)       gates_s[bi][0][d] = si[bi] + sh[bi] + bih;
            else if (g < 256)  gates_s[bi][1][d] = si[bi] + sh[bi] + bih;
            else { gates_s[bi][2][d] = si[bi] + bih; gates_s[bi][3][d] = sh[bi]; }
        }
    }
    __syncthreads();

    // GRU + LN: wave w handles bn (bn0+w); lanes own d = l, l+64
    {
        int bi = t >> 6, l = t & 63;
        float gr[2], s1 = 0.f, s2 = 0.f;
#pragma unroll
        for (int h = 0; h < 2; ++h) {
            int d = l + 64 * h;
            float rr = 1.f / (1.f + __expf(-gates_s[bi][0][d]));
            float ii = 1.f / (1.f + __expf(-gates_s[bi][1][d]));
            float nv = tanhf(gates_s[bi][2][d] + rr * (gates_s[bi][3][d] + b_n[d]));
            float gru = nv + ii * (slot_s[bi][d] - nv);
            gr[h] = gru;
            gru_s[bi][d] = gru;
            s1 += gru; s2 += gru * gru;
        }
#pragma unroll
        for (int m = 1; m < 64; m <<= 1) { s1 += __shfl_xor(s1, m); s2 += __shfl_xor(s2, m); }
        float mu = s1 * (1.0f / 128.0f);
        float var = s2 * (1.0f / 128.0f) - mu * mu;
        float rstd = rsqrtf(var + 1e-5f);
#pragma unroll
        for (int h = 0; h < 2; ++h) {
            int d = l + 64 * h;
            gn_s[bi][d] = (gr[h] - mu) * rstd * ffg[d] + ffb[d];
        }
    }
    __syncthreads();

    // MLP0: thread t = h-row, reuse W0 row across 4 bn
    {
        const float4* w0 = (const float4*)(W0 + (size_t)t * 128);
        float s[4] = {0.f, 0.f, 0.f, 0.f};
#pragma unroll 4
        for (int j = 0; j < 32; ++j) {
            float4 w4 = w0[j];
#pragma unroll
            for (int bi = 0; bi < 4; ++bi) s[bi] += dot4(w4, *(const float4*)&gn_s[bi][4 * j]);
        }
        float b0v = b0[t];
#pragma unroll
        for (int bi = 0; bi < 4; ++bi) h_s[bi][t] = fmaxf(s[bi] + b0v, 0.f);
    }
    __syncthreads();

    // MLP1: t<128 -> row t for bn {0,1}; t>=128 -> row t-128 for bn {2,3}
    {
        int dr = t & 127, bp = (t >> 7) * 2;
        const float4* w1 = (const float4*)(W1 + (size_t)dr * 256);
        float s[2] = {0.f, 0.f};
#pragma unroll 4
        for (int j = 0; j < 64; ++j) {
            float4 w4 = w1[j];
#pragma unroll
            for (int u = 0; u < 2; ++u) s[u] += dot4(w4, *(const float4*)&h_s[bp + u][4 * j]);
        }
        float b1v = b1[dr];
#pragma unroll
        for (int u = 0; u < 2; ++u) {
            int bi = bp + u;
            out[(size_t)(bn0 + bi) * 128 + dr] = gru_s[bi][dr] + s[u] + b1v - slot_s[bi][dr];
        }
    }
}

extern "C" void kernel_launch(void* const* d_in, const int* in_sizes, int n_in,
                              void* d_out, int out_size, void* d_ws, size_t ws_size,
                              hipStream_t stream) {
    const float* slots = (const float*)d_in[1];
    const float* k     = (const float*)d_in[2];
    const float* v     = (const float*)d_in[3];
    const float* Wq    = (const float*)d_in[4];
    const float* lng   = (const float*)d_in[5];
    const float* lnb   = (const float*)d_in[6];
    const float* W_ih  = (const float*)d_in[7];
    const float* W_hh  = (const float*)d_in[8];
    const float* b_ih  = (const float*)d_in[9];
    const float* b_n   = (const float*)d_in[10];
    const float* ffg   = (const float*)d_in[11];
    const float* ffb   = (const float*)d_in[12];
    const float* W0    = (const float*)d_in[13];
    const float* b0    = (const float*)d_in[14];
    const float* W1    = (const float*)d_in[15];
    const float* b1    = (const float*)d_in[16];

    char* ws = (char*)d_ws;
    unsigned int* q_u = (unsigned int*)ws;
    float* acc = (float*)(ws + 262144);
    float* den = (float*)(ws + 786432);

    k_q<<<dim3(B_), dim3(128), 0, stream>>>(slots, Wq, lng, lnb, q_u, acc, den);
    k_attn<<<dim3(16, B_), dim3(256), 0, stream>>>(k, v, q_u, acc, den);
    k_final<<<dim3(256), dim3(256), 0, stream>>>(acc, den, slots, W_ih, W_hh,
                                                 b_ih, b_n, ffg, ffb, W0, b0, W1, b1,
                                                 (float*)d_out);
}